// Round 1
// baseline (611.907 us; speedup 1.0000x reference)
//
#include <hip/hip_runtime.h>
#include <stdint.h>

typedef __attribute__((ext_vector_type(4))) float floatx4;
typedef __attribute__((ext_vector_type(8))) short shortx8;

#define LN_EPS 1e-5f

__device__ __forceinline__ unsigned short f2b(float f) {
  unsigned u = __builtin_bit_cast(unsigned, f);
  u = (u + 0x7FFFu + ((u >> 16) & 1u)) >> 16;
  return (unsigned short)u;
}
__device__ __forceinline__ float b2f(unsigned short h) {
  return __builtin_bit_cast(float, (unsigned)h << 16);
}

// ---------------- block reduction helpers (256 threads = 4 waves) -----------
__device__ __forceinline__ float wave_sum(float v) {
#pragma unroll
  for (int o = 32; o; o >>= 1) v += __shfl_down(v, o, 64);
  return v;
}
__device__ __forceinline__ float wave_max(float v) {
#pragma unroll
  for (int o = 32; o; o >>= 1) v = fmaxf(v, __shfl_down(v, o, 64));
  return v;
}
__device__ __forceinline__ float block_sum(float v, float* s) {
  v = wave_sum(v);
  __syncthreads();
  if ((threadIdx.x & 63) == 0) s[threadIdx.x >> 6] = v;
  __syncthreads();
  return s[0] + s[1] + s[2] + s[3];
}
__device__ __forceinline__ float block_max(float v, float* s) {
  v = wave_max(v);
  __syncthreads();
  if ((threadIdx.x & 63) == 0) s[threadIdx.x >> 6] = v;
  __syncthreads();
  return fmaxf(fmaxf(s[0], s[1]), fmaxf(s[2], s[3]));
}

// ---------------- transpose W (K,N) f32 -> Wt (N,K) bf16 --------------------
__global__ __launch_bounds__(256) void k_transpose_to_bf16(
    const float* __restrict__ in, unsigned short* __restrict__ out, int K, int N) {
  __shared__ float tile[32][33];
  const int k0 = blockIdx.x * 32, n0 = blockIdx.y * 32;
  const int tx = threadIdx.x & 31, ty = threadIdx.x >> 5;  // 32x8
#pragma unroll
  for (int i = 0; i < 32; i += 8)
    tile[ty + i][tx] = in[(long)(k0 + ty + i) * N + n0 + tx];
  __syncthreads();
#pragma unroll
  for (int i = 0; i < 32; i += 8)
    out[(long)(n0 + ty + i) * K + k0 + tx] = f2b(tile[tx][ty + i]);
}

// ---------------- f32 -> bf16 convert ---------------------------------------
__global__ __launch_bounds__(256) void k_cvt_bf16(
    const float* __restrict__ in, unsigned short* __restrict__ out, long n4) {
  long i = ((long)blockIdx.x * 256 + threadIdx.x) * 4;
  floatx4 v = *(const floatx4*)(in + i);
  unsigned short t4[4];
#pragma unroll
  for (int j = 0; j < 4; j++) t4[j] = f2b(v[j]);
  *(uint2*)(out + i) = *(uint2*)t4;
  (void)n4;
}

// ---------------- generic bf16 MFMA GEMM, 64x64 tile, fused epilogues -------
// C[m][n] = sum_k A[m][k] * Bt[n][k]  (Bt = B transposed, bf16)
// modes: 0: out bf16 = v+bias          (proj)
//        1: out f32  = sigmoid(v+bias) (u)
//        2: out bf16 = sigmoid(v+bias)*psn[row*2048+c]  (r -> r*ps_n)
//        3: out f32  = (1-u)*prev + u*tanh(v+bias)      (cand -> new_state)
//        4: out f32  = v*scale         (scores)
__global__ __launch_bounds__(256) void k_gemm_bf16(
    const void* __restrict__ Aptr, int lda, long sA, int a_is_f32,
    const unsigned short* __restrict__ Bt, int ldb, long sB, int K,
    const float* __restrict__ bias, float scale, int mode,
    void* __restrict__ out, int ldc, long sC,
    const unsigned short* __restrict__ aux_psn,
    const float* __restrict__ aux_u, const float* __restrict__ aux_prev) {
  __shared__ unsigned short As[64 * 40];  // +8 pad: 2-way-max frag read conflicts
  __shared__ unsigned short Bs[64 * 40];
  const int tid = threadIdx.x;
  const int b = blockIdx.z;
  const int m0 = blockIdx.x * 64, n0 = blockIdx.y * 64;
  const int w = tid >> 6, lane = tid & 63;
  const int wm = w & 1, wn = w >> 1;
  const int l16 = lane & 15, quad = lane >> 4;
  const int srow = tid >> 2, skc = (tid & 3) * 8;

  floatx4 acc[2][2] = {};

  for (int k0 = 0; k0 < K; k0 += 32) {
    if (a_is_f32) {
      const float* src = (const float*)Aptr + (long)b * sA + (long)(m0 + srow) * lda + k0 + skc;
      floatx4 v0 = *(const floatx4*)src;
      floatx4 v1 = *(const floatx4*)(src + 4);
      unsigned short t8[8];
#pragma unroll
      for (int i = 0; i < 4; i++) { t8[i] = f2b(v0[i]); t8[i + 4] = f2b(v1[i]); }
      *(uint4*)&As[srow * 40 + skc] = *(uint4*)t8;
    } else {
      const unsigned short* src =
          (const unsigned short*)Aptr + (long)b * sA + (long)(m0 + srow) * lda + k0 + skc;
      *(uint4*)&As[srow * 40 + skc] = *(const uint4*)src;
    }
    {
      const unsigned short* src = Bt + (long)b * sB + (long)(n0 + srow) * ldb + k0 + skc;
      *(uint4*)&Bs[srow * 40 + skc] = *(const uint4*)src;
    }
    __syncthreads();

    shortx8 a0 = *(const shortx8*)&As[(wm * 32 + 0  + l16) * 40 + quad * 8];
    shortx8 a1 = *(const shortx8*)&As[(wm * 32 + 16 + l16) * 40 + quad * 8];
    shortx8 b0 = *(const shortx8*)&Bs[(wn * 32 + 0  + l16) * 40 + quad * 8];
    shortx8 b1 = *(const shortx8*)&Bs[(wn * 32 + 16 + l16) * 40 + quad * 8];
    acc[0][0] = __builtin_amdgcn_mfma_f32_16x16x32_bf16(a0, b0, acc[0][0], 0, 0, 0);
    acc[0][1] = __builtin_amdgcn_mfma_f32_16x16x32_bf16(a0, b1, acc[0][1], 0, 0, 0);
    acc[1][0] = __builtin_amdgcn_mfma_f32_16x16x32_bf16(a1, b0, acc[1][0], 0, 0, 0);
    acc[1][1] = __builtin_amdgcn_mfma_f32_16x16x32_bf16(a1, b1, acc[1][1], 0, 0, 0);
    __syncthreads();
  }

#pragma unroll
  for (int im = 0; im < 2; im++)
#pragma unroll
    for (int in_ = 0; in_ < 2; in_++) {
      const int rbase = m0 + wm * 32 + im * 16 + quad * 4;
      const int c = n0 + wn * 32 + in_ * 16 + l16;
      const float bval = bias ? bias[c] : 0.0f;
#pragma unroll
      for (int r = 0; r < 4; r++) {
        const int row = rbase + r;
        float v = acc[im][in_][r] * scale + bval;
        const long cidx = (long)b * sC + (long)row * ldc + c;
        if (mode == 0) {
          ((unsigned short*)out)[cidx] = f2b(v);
        } else if (mode == 1) {
          ((float*)out)[cidx] = 1.0f / (1.0f + expf(-v));
        } else if (mode == 2) {
          float rr = 1.0f / (1.0f + expf(-v));
          ((unsigned short*)out)[cidx] = f2b(rr * b2f(aux_psn[(long)row * 2048 + c]));
        } else if (mode == 3) {
          float cand = tanhf(v);
          float u = aux_u[(long)row * 1024 + c];
          float p = aux_prev[(long)row * 1024 + c];
          ((float*)out)[cidx] = (1.0f - u) * p + u * cand;
        } else {
          ((float*)out)[cidx] = v;
        }
      }
    }
}

// ---------------- softmax over S=2048, one row per block --------------------
__global__ __launch_bounds__(256) void k_softmax(float* __restrict__ attn) {
  __shared__ float scr[4];
  float* row = attn + (long)blockIdx.x * 2048;
  const int t = threadIdx.x;
  floatx4 a = *(const floatx4*)(row + t * 8);
  floatx4 b = *(const floatx4*)(row + t * 8 + 4);
  float m = -1e30f;
#pragma unroll
  for (int i = 0; i < 4; i++) m = fmaxf(m, fmaxf(a[i], b[i]));
  m = block_max(m, scr);
  float s = 0.f;
#pragma unroll
  for (int i = 0; i < 4; i++) { a[i] = expf(a[i] - m); s += a[i]; b[i] = expf(b[i] - m); s += b[i]; }
  s = block_sum(s, scr);
  const float inv = 1.0f / s;
#pragma unroll
  for (int i = 0; i < 4; i++) { a[i] *= inv; b[i] *= inv; }
  *(floatx4*)(row + t * 8) = a;
  *(floatx4*)(row + t * 8 + 4) = b;
}

// ---------------- routed = attn @ tok, s-split into 4 partials --------------
// grid (dt=4, sc=4, b=16); block tile: 64 n x 256 d, K = 512 s
__global__ __launch_bounds__(256) void k_routed(
    const float* __restrict__ attn, const unsigned short* __restrict__ tok,
    float* __restrict__ parts) {
  __shared__ float a_t[64 * 17];
  __shared__ float t_t[16 * 264];
  const int dt = blockIdx.x, sc = blockIdx.y, b = blockIdx.z;
  const int t = threadIdx.x;
  const int nt = t & 15;   // lanes vary n -> a_t reads 2-way max
  const int d2 = t >> 4;   // t_t reads broadcast within 16 lanes
  const int d0 = dt * 256;
  const int sn = t >> 2, ssi = (t & 3) * 4;
  const int ts = t >> 4, tdi = (t & 15) * 16;
  floatx4 acc[4][4] = {};

  for (int s0 = sc * 512; s0 < sc * 512 + 512; s0 += 16) {
    {
      floatx4 av = *(const floatx4*)(attn + (long)(b * 64 + sn) * 2048 + s0 + ssi);
#pragma unroll
      for (int i = 0; i < 4; i++) a_t[sn * 17 + ssi + i] = av[i];
    }
    {
      const unsigned short* src = tok + (long)(b * 2048 + s0 + ts) * 1024 + d0 + tdi;
      uint4 u0 = *(const uint4*)src;
      uint4 u1 = *(const uint4*)(src + 8);
      const unsigned short* p0 = (const unsigned short*)&u0;
      const unsigned short* p1 = (const unsigned short*)&u1;
      float* dst = &t_t[ts * 264 + tdi];
#pragma unroll
      for (int i = 0; i < 8; i++) { dst[i] = b2f(p0[i]); dst[8 + i] = b2f(p1[i]); }
    }
    __syncthreads();
#pragma unroll
    for (int ss = 0; ss < 16; ss++) {
      const float a0 = a_t[(nt * 4 + 0) * 17 + ss];
      const float a1 = a_t[(nt * 4 + 1) * 17 + ss];
      const float a2 = a_t[(nt * 4 + 2) * 17 + ss];
      const float a3 = a_t[(nt * 4 + 3) * 17 + ss];
      const floatx4* tp = (const floatx4*)&t_t[ss * 264 + d2 * 16];
      floatx4 t0 = tp[0], t1 = tp[1], t2 = tp[2], t3 = tp[3];
      acc[0][0] += a0 * t0; acc[0][1] += a0 * t1; acc[0][2] += a0 * t2; acc[0][3] += a0 * t3;
      acc[1][0] += a1 * t0; acc[1][1] += a1 * t1; acc[1][2] += a1 * t2; acc[1][3] += a1 * t3;
      acc[2][0] += a2 * t0; acc[2][1] += a2 * t1; acc[2][2] += a2 * t2; acc[2][3] += a2 * t3;
      acc[3][0] += a3 * t0; acc[3][1] += a3 * t1; acc[3][2] += a3 * t2; acc[3][3] += a3 * t3;
    }
    __syncthreads();
  }
  float* base = parts + (long)sc * 1048576 + (long)(b * 64) * 1024 + d0 + d2 * 16;
#pragma unroll
  for (int i = 0; i < 4; i++)
#pragma unroll
    for (int j = 0; j < 4; j++)
      *(floatx4*)(base + (long)(nt * 4 + i) * 1024 + j * 4) = acc[i][j];
}

// ---------------- LayerNorm (D=1024) -> bf16 target(s) ----------------------
__global__ __launch_bounds__(256) void k_ln_bf16(
    const float* __restrict__ in, int nparts,
    const float* __restrict__ g, const float* __restrict__ be,
    unsigned short* __restrict__ out0, int ld0, int off0,
    unsigned short* __restrict__ out1, int ld1, int off1) {
  __shared__ float scr[4];
  const long r = blockIdx.x;
  const int t = threadIdx.x;
  floatx4 v = {};
  for (int p = 0; p < nparts; p++)
    v += *(const floatx4*)(in + (long)p * 1048576 + r * 1024 + t * 4);
  float s1 = v[0] + v[1] + v[2] + v[3];
  float s2 = v[0] * v[0] + v[1] * v[1] + v[2] * v[2] + v[3] * v[3];
  s1 = block_sum(s1, scr);
  s2 = block_sum(s2, scr);
  const float mean = s1 * (1.0f / 1024.0f);
  const float var = s2 * (1.0f / 1024.0f) - mean * mean;
  const float rstd = rsqrtf(var + LN_EPS);
#pragma unroll
  for (int i = 0; i < 4; i++) {
    const int d = t * 4 + i;
    const float y = (v[i] - mean) * rstd * g[d] + be[d];
    const unsigned short h = f2b(y);
    out0[r * ld0 + off0 + d] = h;
    if (out1) out1[r * ld1 + off1 + d] = h;
  }
}

// ---------------- final LayerNorm -> f32 output ------------------------------
__global__ __launch_bounds__(256) void k_ln_out(
    const float* __restrict__ in, const float* __restrict__ g,
    const float* __restrict__ be, float* __restrict__ out) {
  __shared__ float scr[4];
  const long r = blockIdx.x;
  const int t = threadIdx.x;
  floatx4 v = *(const floatx4*)(in + r * 1024 + t * 4);
  float s1 = v[0] + v[1] + v[2] + v[3];
  float s2 = v[0] * v[0] + v[1] * v[1] + v[2] * v[2] + v[3] * v[3];
  s1 = block_sum(s1, scr);
  s2 = block_sum(s2, scr);
  const float mean = s1 * (1.0f / 1024.0f);
  const float var = s2 * (1.0f / 1024.0f) - mean * mean;
  const float rstd = rsqrtf(var + LN_EPS);
  floatx4 o;
#pragma unroll
  for (int i = 0; i < 4; i++) {
    const int d = t * 4 + i;
    o[i] = (v[i] - mean) * rstd * g[d] + be[d];
  }
  *(floatx4*)(out + r * 1024 + t * 4) = o;
}

// ---------------------------------------------------------------------------
extern "C" void kernel_launch(void* const* d_in, const int* in_sizes, int n_in,
                              void* d_out, int out_size, void* d_ws, size_t ws_size,
                              hipStream_t stream) {
  (void)in_sizes; (void)n_in; (void)out_size; (void)ws_size;
  const float* prev  = (const float*)d_in[0];
  const float* toks  = (const float*)d_in[1];
  const float* Wp    = (const float*)d_in[2];
  const float* bp    = (const float*)d_in[3];
  const float* g_st  = (const float*)d_in[4];
  const float* be_st = (const float*)d_in[5];
  const float* g_in  = (const float*)d_in[6];
  const float* be_in = (const float*)d_in[7];
  const float* g_o   = (const float*)d_in[8];
  const float* be_o  = (const float*)d_in[9];
  const float* Wu    = (const float*)d_in[10];
  const float* bu    = (const float*)d_in[11];
  const float* Wr    = (const float*)d_in[12];
  const float* br    = (const float*)d_in[13];
  const float* Wn    = (const float*)d_in[14];
  const float* bn    = (const float*)d_in[15];
  float* out = (float*)d_out;

  char* ws = (char*)d_ws;
  unsigned short* tok   = (unsigned short*)ws; ws += 67108864;   // 32768x1024 bf16
  unsigned short* Wtp   = (unsigned short*)ws; ws += 1572864;    // 1024x768
  unsigned short* Wtu   = (unsigned short*)ws; ws += 4194304;    // 1024x2048
  unsigned short* Wtr   = (unsigned short*)ws; ws += 4194304;
  unsigned short* Wtn   = (unsigned short*)ws; ws += 4194304;
  unsigned short* psb   = (unsigned short*)ws; ws += 2097152;    // 1024x1024 bf16
  float*          attn  = (float*)ws;          ws += 8388608;    // 16x64x2048 f32
  float*          parts = (float*)ws;          ws += 16777216;   // 4x 1024x1024 f32
  unsigned short* conc  = (unsigned short*)ws; ws += 4194304;    // 1024x2048 bf16
  unsigned short* candA = (unsigned short*)ws; ws += 4194304;    // 1024x2048 bf16
  float*          ubuf  = (float*)ws;          ws += 4194304;    // 1024x1024 f32
  float*          ns    = (float*)ws;          ws += 4194304;    // 1024x1024 f32

  const dim3 blk(256);

  // weight transposes to bf16 [n][k]
  k_transpose_to_bf16<<<dim3(24, 32), blk, 0, stream>>>(Wp, Wtp, 768, 1024);
  k_transpose_to_bf16<<<dim3(64, 32), blk, 0, stream>>>(Wu, Wtu, 2048, 1024);
  k_transpose_to_bf16<<<dim3(64, 32), blk, 0, stream>>>(Wr, Wtr, 2048, 1024);
  k_transpose_to_bf16<<<dim3(64, 32), blk, 0, stream>>>(Wn, Wtn, 2048, 1024);
  // prev_states -> bf16 (raw, for attention scores)
  k_cvt_bf16<<<dim3(1024), blk, 0, stream>>>(prev, psb, 1048576);

  // tok = input_tokens @ W_proj + b_proj  -> bf16 (mode 0)
  k_gemm_bf16<<<dim3(512, 16, 1), blk, 0, stream>>>(
      (const void*)toks, 768, 0L, 1, Wtp, 768, 0L, 768,
      bp, 1.0f, 0, (void*)tok, 1024, 0L, nullptr, nullptr, nullptr);

  // scores = prev @ tok^T / 32  (batched, mode 4)
  k_gemm_bf16<<<dim3(1, 32, 16), blk, 0, stream>>>(
      (const void*)psb, 1024, 65536L, 0, tok, 1024, 2097152L, 1024,
      nullptr, 0.03125f, 4, (void*)attn, 2048, 131072L, nullptr, nullptr, nullptr);

  k_softmax<<<dim3(1024), blk, 0, stream>>>(attn);

  // routed partials
  k_routed<<<dim3(4, 4, 16), blk, 0, stream>>>(attn, tok, parts);

  // ps_n = LN(prev) -> concat[:, :1024]
  k_ln_bf16<<<dim3(1024), blk, 0, stream>>>(
      prev, 1, g_st, be_st, conc, 2048, 0, nullptr, 0, 0);
  // in_n = LN(sum parts) -> concat[:, 1024:] and candA[:, 1024:]
  k_ln_bf16<<<dim3(1024), blk, 0, stream>>>(
      parts, 4, g_in, be_in, conc, 2048, 1024, candA, 2048, 1024);

  // u = sigmoid(concat @ W_u + b_u)   (mode 1)
  k_gemm_bf16<<<dim3(16, 16, 1), blk, 0, stream>>>(
      (const void*)conc, 2048, 0L, 0, Wtu, 2048, 0L, 2048,
      bu, 1.0f, 1, (void*)ubuf, 1024, 0L, nullptr, nullptr, nullptr);
  // r*ps_n -> candA[:, :1024]        (mode 2)
  k_gemm_bf16<<<dim3(16, 16, 1), blk, 0, stream>>>(
      (const void*)conc, 2048, 0L, 0, Wtr, 2048, 0L, 2048,
      br, 1.0f, 2, (void*)candA, 2048, 0L, conc, nullptr, nullptr);
  // new_state = (1-u)*prev + u*tanh(candA @ W_n + b_n)  (mode 3)
  k_gemm_bf16<<<dim3(16, 16, 1), blk, 0, stream>>>(
      (const void*)candA, 2048, 0L, 0, Wtn, 2048, 0L, 2048,
      bn, 1.0f, 3, (void*)ns, 1024, 0L, nullptr, ubuf, prev);

  // final LN -> output (f32)
  k_ln_out<<<dim3(1024), blk, 0, stream>>>(ns, g_o, be_o, out);
}

// Round 2
// 489.633 us; speedup vs baseline: 1.2497x; 1.2497x over previous
//
#include <hip/hip_runtime.h>
#include <stdint.h>

typedef __attribute__((ext_vector_type(4))) float floatx4;
typedef __attribute__((ext_vector_type(8))) short shortx8;

#define LN_EPS 1e-5f

__device__ __forceinline__ unsigned short f2b(float f) {
  unsigned u = __builtin_bit_cast(unsigned, f);
  u = (u + 0x7FFFu + ((u >> 16) & 1u)) >> 16;
  return (unsigned short)u;
}
__device__ __forceinline__ float b2f(unsigned short h) {
  return __builtin_bit_cast(float, (unsigned)h << 16);
}

// async global->LDS 16B: lds dest must be wave-uniform base; lane i lands at base + i*16
__device__ __forceinline__ void g2l16(const unsigned short* g, unsigned short* l) {
  __builtin_amdgcn_global_load_lds(
      (const __attribute__((address_space(1))) unsigned int*)g,
      (__attribute__((address_space(3))) unsigned int*)l, 16, 0, 0);
}

// ---------------- block reduction helpers (256 threads = 4 waves) -----------
__device__ __forceinline__ float wave_sum(float v) {
#pragma unroll
  for (int o = 32; o; o >>= 1) v += __shfl_down(v, o, 64);
  return v;
}
__device__ __forceinline__ float wave_max(float v) {
#pragma unroll
  for (int o = 32; o; o >>= 1) v = fmaxf(v, __shfl_down(v, o, 64));
  return v;
}
__device__ __forceinline__ float block_sum(float v, float* s) {
  v = wave_sum(v);
  __syncthreads();
  if ((threadIdx.x & 63) == 0) s[threadIdx.x >> 6] = v;
  __syncthreads();
  return s[0] + s[1] + s[2] + s[3];
}
__device__ __forceinline__ float block_max(float v, float* s) {
  v = wave_max(v);
  __syncthreads();
  if ((threadIdx.x & 63) == 0) s[threadIdx.x >> 6] = v;
  __syncthreads();
  return fmaxf(fmaxf(s[0], s[1]), fmaxf(s[2], s[3]));
}

// ---------------- transpose W (K,N) f32 -> Wt (N,K) bf16 --------------------
__global__ __launch_bounds__(256) void k_transpose_to_bf16(
    const float* __restrict__ in, unsigned short* __restrict__ out, int K, int N) {
  __shared__ float tile[32][33];
  const int k0 = blockIdx.x * 32, n0 = blockIdx.y * 32;
  const int tx = threadIdx.x & 31, ty = threadIdx.x >> 5;  // 32x8
#pragma unroll
  for (int i = 0; i < 32; i += 8)
    tile[ty + i][tx] = in[(long)(k0 + ty + i) * N + n0 + tx];
  __syncthreads();
#pragma unroll
  for (int i = 0; i < 32; i += 8)
    out[(long)(n0 + ty + i) * K + k0 + tx] = f2b(tile[tx][ty + i]);
}

// ---------------- f32 -> bf16 convert ---------------------------------------
__global__ __launch_bounds__(256) void k_cvt_bf16(
    const float* __restrict__ in, unsigned short* __restrict__ out) {
  long i = ((long)blockIdx.x * 256 + threadIdx.x) * 4;
  floatx4 v = *(const floatx4*)(in + i);
  unsigned short t4[4];
#pragma unroll
  for (int j = 0; j < 4; j++) t4[j] = f2b(v[j]);
  *(uint2*)(out + i) = *(uint2*)t4;
}

// ---------------- proj: 128x128 MFMA GEMM (m97 structure) -------------------
// C[m][n] = A[m][k] * Bt[n][k] + bias[n], bf16 in / bf16 out. K=768, N=1024.
__global__ __launch_bounds__(256) void k_proj128(
    const unsigned short* __restrict__ A, const unsigned short* __restrict__ Bt,
    const float* __restrict__ bias, unsigned short* __restrict__ C) {
  constexpr int K = 768;
  constexpr int N = 1024;
  __shared__ unsigned short As[128 * 32];
  __shared__ unsigned short Bs[128 * 32];
  const int tid = threadIdx.x;
  const int wave = tid >> 6, lane = tid & 63;
  const int n0 = blockIdx.x * 128, m0 = blockIdx.y * 128;  // n fastest: L2 A-reuse
  const int wm = wave & 1, wn = wave >> 1;
  const int l16 = lane & 15, quad = lane >> 4;
  const int srow = lane >> 2;          // 0..15 within a 16-row region
  const int skc = (lane & 3) * 8;      // k-chunk (8 bf16 = 16B)

  floatx4 acc[4][4] = {};

  for (int k0 = 0; k0 < K; k0 += 32) {
#pragma unroll
    for (int j = 0; j < 2; j++) {
      const int reg = wave * 2 + j;              // 8 regions of 16 rows
      const int row = reg * 16 + srow;
      g2l16(A + (long)(m0 + row) * K + k0 + skc, &As[reg * 512]);
      g2l16(Bt + (long)(n0 + row) * K + k0 + skc, &Bs[reg * 512]);
    }
    __syncthreads();

    shortx8 af[4], bf[4];
#pragma unroll
    for (int i = 0; i < 4; i++)
      af[i] = *(const shortx8*)&As[(wm * 64 + i * 16 + l16) * 32 + quad * 8];
#pragma unroll
    for (int i = 0; i < 4; i++)
      bf[i] = *(const shortx8*)&Bs[(wn * 64 + i * 16 + l16) * 32 + quad * 8];
#pragma unroll
    for (int i = 0; i < 4; i++)
#pragma unroll
      for (int j = 0; j < 4; j++)
        acc[i][j] = __builtin_amdgcn_mfma_f32_16x16x32_bf16(af[i], bf[j], acc[i][j], 0, 0, 0);
    __syncthreads();
  }

#pragma unroll
  for (int i = 0; i < 4; i++)
#pragma unroll
    for (int j = 0; j < 4; j++) {
      const int rbase = m0 + wm * 64 + i * 16 + quad * 4;
      const int col = n0 + wn * 64 + j * 16 + l16;
      const float bval = bias[col];
#pragma unroll
      for (int r = 0; r < 4; r++)
        C[(long)(rbase + r) * N + col] = f2b(acc[i][j][r] + bval);
    }
}

// ---------------- generic bf16 MFMA GEMM, 64x64 tile, fused epilogues -------
// modes: 1: out f32  = sigmoid(v+bias) (u)
//        3: out f32  = (1-u)*prev + u*tanh(v+bias)      (cand -> new_state)
//        4: out f32  = v*scale         (scores)
//        5: c<1024: out f32 = sigmoid(v+bias) (u); c>=1024: out2 bf16 = sigmoid*psn (r)
__global__ __launch_bounds__(256) void k_gemm_bf16(
    const unsigned short* __restrict__ Aptr, int lda, long sA,
    const unsigned short* __restrict__ Bt, int ldb, long sB, int K,
    const float* __restrict__ bias, float scale, int mode,
    void* __restrict__ out, int ldc, long sC, unsigned short* __restrict__ out2,
    const unsigned short* __restrict__ aux_psn,
    const float* __restrict__ aux_u, const float* __restrict__ aux_prev) {
  __shared__ unsigned short As[64 * 40];
  __shared__ unsigned short Bs[64 * 40];
  const int tid = threadIdx.x;
  const int b = blockIdx.z;
  const int m0 = blockIdx.x * 64, n0 = blockIdx.y * 64;
  const int w = tid >> 6, lane = tid & 63;
  const int wm = w & 1, wn = w >> 1;
  const int l16 = lane & 15, quad = lane >> 4;
  const int srow = tid >> 2, skc = (tid & 3) * 8;

  floatx4 acc[2][2] = {};

  for (int k0 = 0; k0 < K; k0 += 32) {
    {
      const unsigned short* src = Aptr + (long)b * sA + (long)(m0 + srow) * lda + k0 + skc;
      *(uint4*)&As[srow * 40 + skc] = *(const uint4*)src;
    }
    {
      const unsigned short* src = Bt + (long)b * sB + (long)(n0 + srow) * ldb + k0 + skc;
      *(uint4*)&Bs[srow * 40 + skc] = *(const uint4*)src;
    }
    __syncthreads();

    shortx8 a0 = *(const shortx8*)&As[(wm * 32 + 0  + l16) * 40 + quad * 8];
    shortx8 a1 = *(const shortx8*)&As[(wm * 32 + 16 + l16) * 40 + quad * 8];
    shortx8 b0 = *(const shortx8*)&Bs[(wn * 32 + 0  + l16) * 40 + quad * 8];
    shortx8 b1 = *(const shortx8*)&Bs[(wn * 32 + 16 + l16) * 40 + quad * 8];
    acc[0][0] = __builtin_amdgcn_mfma_f32_16x16x32_bf16(a0, b0, acc[0][0], 0, 0, 0);
    acc[0][1] = __builtin_amdgcn_mfma_f32_16x16x32_bf16(a0, b1, acc[0][1], 0, 0, 0);
    acc[1][0] = __builtin_amdgcn_mfma_f32_16x16x32_bf16(a1, b0, acc[1][0], 0, 0, 0);
    acc[1][1] = __builtin_amdgcn_mfma_f32_16x16x32_bf16(a1, b1, acc[1][1], 0, 0, 0);
    __syncthreads();
  }

#pragma unroll
  for (int im = 0; im < 2; im++)
#pragma unroll
    for (int in_ = 0; in_ < 2; in_++) {
      const int rbase = m0 + wm * 32 + im * 16 + quad * 4;
      const int c = n0 + wn * 32 + in_ * 16 + l16;
      const float bval = bias ? bias[c] : 0.0f;
#pragma unroll
      for (int r = 0; r < 4; r++) {
        const int row = rbase + r;
        float v = acc[im][in_][r] * scale + bval;
        const long cidx = (long)b * sC + (long)row * ldc + c;
        if (mode == 1) {
          ((float*)out)[cidx] = 1.0f / (1.0f + expf(-v));
        } else if (mode == 3) {
          float cand = tanhf(v);
          float u = aux_u[(long)row * 1024 + c];
          float p = aux_prev[(long)row * 1024 + c];
          ((float*)out)[cidx] = (1.0f - u) * p + u * cand;
        } else if (mode == 4) {
          ((float*)out)[cidx] = v;
        } else {  // mode 5: merged u|r
          if (c < 1024) {
            ((float*)out)[(long)row * 1024 + c] = 1.0f / (1.0f + expf(-v));
          } else {
            const int cc = c - 1024;
            float rr = 1.0f / (1.0f + expf(-v));
            out2[(long)row * 2048 + cc] = f2b(rr * b2f(aux_psn[(long)row * 2048 + cc]));
          }
        }
      }
    }
}

// ---------------- softmax over S=2048, one row per block --------------------
__global__ __launch_bounds__(256) void k_softmax(float* __restrict__ attn) {
  __shared__ float scr[4];
  float* row = attn + (long)blockIdx.x * 2048;
  const int t = threadIdx.x;
  floatx4 a = *(const floatx4*)(row + t * 8);
  floatx4 b = *(const floatx4*)(row + t * 8 + 4);
  float m = -1e30f;
#pragma unroll
  for (int i = 0; i < 4; i++) m = fmaxf(m, fmaxf(a[i], b[i]));
  m = block_max(m, scr);
  float s = 0.f;
#pragma unroll
  for (int i = 0; i < 4; i++) { a[i] = expf(a[i] - m); s += a[i]; b[i] = expf(b[i] - m); s += b[i]; }
  s = block_sum(s, scr);
  const float inv = 1.0f / s;
#pragma unroll
  for (int i = 0; i < 4; i++) { a[i] *= inv; b[i] *= inv; }
  *(floatx4*)(row + t * 8) = a;
  *(floatx4*)(row + t * 8 + 4) = b;
}

// ---------------- routed = attn @ tok, s-split into 4 partials --------------
__global__ __launch_bounds__(256) void k_routed(
    const float* __restrict__ attn, const unsigned short* __restrict__ tok,
    float* __restrict__ parts) {
  __shared__ float a_t[64 * 17];
  __shared__ float t_t[16 * 264];
  const int dt = blockIdx.x, sc = blockIdx.y, b = blockIdx.z;
  const int t = threadIdx.x;
  const int nt = t & 15;
  const int d2 = t >> 4;
  const int d0 = dt * 256;
  const int sn = t >> 2, ssi = (t & 3) * 4;
  const int ts = t >> 4, tdi = (t & 15) * 16;
  floatx4 acc[4][4] = {};

  for (int s0 = sc * 512; s0 < sc * 512 + 512; s0 += 16) {
    {
      floatx4 av = *(const floatx4*)(attn + (long)(b * 64 + sn) * 2048 + s0 + ssi);
#pragma unroll
      for (int i = 0; i < 4; i++) a_t[sn * 17 + ssi + i] = av[i];
    }
    {
      const unsigned short* src = tok + (long)(b * 2048 + s0 + ts) * 1024 + d0 + tdi;
      uint4 u0 = *(const uint4*)src;
      uint4 u1 = *(const uint4*)(src + 8);
      const unsigned short* p0 = (const unsigned short*)&u0;
      const unsigned short* p1 = (const unsigned short*)&u1;
      float* dst = &t_t[ts * 264 + tdi];
#pragma unroll
      for (int i = 0; i < 8; i++) { dst[i] = b2f(p0[i]); dst[8 + i] = b2f(p1[i]); }
    }
    __syncthreads();
#pragma unroll
    for (int ss = 0; ss < 16; ss++) {
      const float a0 = a_t[(nt * 4 + 0) * 17 + ss];
      const float a1 = a_t[(nt * 4 + 1) * 17 + ss];
      const float a2 = a_t[(nt * 4 + 2) * 17 + ss];
      const float a3 = a_t[(nt * 4 + 3) * 17 + ss];
      const floatx4* tp = (const floatx4*)&t_t[ss * 264 + d2 * 16];
      floatx4 t0 = tp[0], t1 = tp[1], t2 = tp[2], t3 = tp[3];
      acc[0][0] += a0 * t0; acc[0][1] += a0 * t1; acc[0][2] += a0 * t2; acc[0][3] += a0 * t3;
      acc[1][0] += a1 * t0; acc[1][1] += a1 * t1; acc[1][2] += a1 * t2; acc[1][3] += a1 * t3;
      acc[2][0] += a2 * t0; acc[2][1] += a2 * t1; acc[2][2] += a2 * t2; acc[2][3] += a2 * t3;
      acc[3][0] += a3 * t0; acc[3][1] += a3 * t1; acc[3][2] += a3 * t2; acc[3][3] += a3 * t3;
    }
    __syncthreads();
  }
  float* base = parts + (long)sc * 1048576 + (long)(b * 64) * 1024 + d0 + d2 * 16;
#pragma unroll
  for (int i = 0; i < 4; i++)
#pragma unroll
    for (int j = 0; j < 4; j++)
      *(floatx4*)(base + (long)(nt * 4 + i) * 1024 + j * 4) = acc[i][j];
}

// ---------------- LayerNorm (D=1024) -> bf16 target(s) ----------------------
__global__ __launch_bounds__(256) void k_ln_bf16(
    const float* __restrict__ in, int nparts,
    const float* __restrict__ g, const float* __restrict__ be,
    unsigned short* __restrict__ out0, int ld0, int off0,
    unsigned short* __restrict__ out1, int ld1, int off1) {
  __shared__ float scr[4];
  const long r = blockIdx.x;
  const int t = threadIdx.x;
  floatx4 v = {};
  for (int p = 0; p < nparts; p++)
    v += *(const floatx4*)(in + (long)p * 1048576 + r * 1024 + t * 4);
  float s1 = v[0] + v[1] + v[2] + v[3];
  float s2 = v[0] * v[0] + v[1] * v[1] + v[2] * v[2] + v[3] * v[3];
  s1 = block_sum(s1, scr);
  s2 = block_sum(s2, scr);
  const float mean = s1 * (1.0f / 1024.0f);
  const float var = s2 * (1.0f / 1024.0f) - mean * mean;
  const float rstd = rsqrtf(var + LN_EPS);
#pragma unroll
  for (int i = 0; i < 4; i++) {
    const int d = t * 4 + i;
    const float y = (v[i] - mean) * rstd * g[d] + be[d];
    const unsigned short h = f2b(y);
    out0[r * ld0 + off0 + d] = h;
    if (out1) out1[r * ld1 + off1 + d] = h;
  }
}

// ---------------- final LayerNorm -> f32 output ------------------------------
__global__ __launch_bounds__(256) void k_ln_out(
    const float* __restrict__ in, const float* __restrict__ g,
    const float* __restrict__ be, float* __restrict__ out) {
  __shared__ float scr[4];
  const long r = blockIdx.x;
  const int t = threadIdx.x;
  floatx4 v = *(const floatx4*)(in + r * 1024 + t * 4);
  float s1 = v[0] + v[1] + v[2] + v[3];
  float s2 = v[0] * v[0] + v[1] * v[1] + v[2] * v[2] + v[3] * v[3];
  s1 = block_sum(s1, scr);
  s2 = block_sum(s2, scr);
  const float mean = s1 * (1.0f / 1024.0f);
  const float var = s2 * (1.0f / 1024.0f) - mean * mean;
  const float rstd = rsqrtf(var + LN_EPS);
  floatx4 o;
#pragma unroll
  for (int i = 0; i < 4; i++) {
    const int d = t * 4 + i;
    o[i] = (v[i] - mean) * rstd * g[d] + be[d];
  }
  *(floatx4*)(out + r * 1024 + t * 4) = o;
}

// ---------------------------------------------------------------------------
extern "C" void kernel_launch(void* const* d_in, const int* in_sizes, int n_in,
                              void* d_out, int out_size, void* d_ws, size_t ws_size,
                              hipStream_t stream) {
  (void)in_sizes; (void)n_in; (void)out_size; (void)ws_size;
  const float* prev  = (const float*)d_in[0];
  const float* toks  = (const float*)d_in[1];
  const float* Wp    = (const float*)d_in[2];
  const float* bp    = (const float*)d_in[3];
  const float* g_st  = (const float*)d_in[4];
  const float* be_st = (const float*)d_in[5];
  const float* g_in  = (const float*)d_in[6];
  const float* be_in = (const float*)d_in[7];
  const float* g_o   = (const float*)d_in[8];
  const float* be_o  = (const float*)d_in[9];
  const float* Wu    = (const float*)d_in[10];
  const float* bu    = (const float*)d_in[11];
  const float* Wr    = (const float*)d_in[12];
  const float* br    = (const float*)d_in[13];
  const float* Wn    = (const float*)d_in[14];
  const float* bn    = (const float*)d_in[15];
  float* out = (float*)d_out;

  // ---- workspace layout (~125.3 MB). Region U aliases bt_toks (dead after
  // proj) with everything produced/consumed after proj.
  char* ws = (char*)d_ws;
  unsigned short* tok   = (unsigned short*)ws; ws += 67108864;   // 32768x1024 bf16
  unsigned short* Wtp   = (unsigned short*)ws; ws += 1572864;    // 1024x768 bf16
  unsigned short* psb   = (unsigned short*)ws; ws += 2097152;    // 1024x1024 bf16
  char* U = ws;
  unsigned short* bt_toks = (unsigned short*)U;                  // 32768x768 bf16 (50.3MB)
  char* u = U;
  float*          attn  = (float*)u;          u += 8388608;      // 16x64x2048 f32
  float*          parts = (float*)u;          u += 16777216;     // 4x 1024x1024 f32
  unsigned short* conc  = (unsigned short*)u; u += 4194304;      // 1024x2048 bf16
  unsigned short* candA = (unsigned short*)u; u += 4194304;      // 1024x2048 bf16
  float*          ubuf  = (float*)u;          u += 4194304;      // 1024x1024 f32
  float*          ns    = (float*)u;          u += 4194304;      // 1024x1024 f32
  unsigned short* Wtur  = (unsigned short*)u; u += 8388608;      // 2048x2048 bf16
  unsigned short* Wtn   = (unsigned short*)u; u += 4194304;      // 1024x2048 bf16
  float*          b_ur  = (float*)u;          u += 8192;         // 2048 f32

  const dim3 blk(256);

  // ---- pre-proj: convert A-side operands (Wtp/psb/bt_toks live outside/inside U)
  k_transpose_to_bf16<<<dim3(24, 32), blk, 0, stream>>>(Wp, Wtp, 768, 1024);
  k_cvt_bf16<<<dim3(1024), blk, 0, stream>>>(prev, psb);
  k_cvt_bf16<<<dim3(24576), blk, 0, stream>>>(toks, bt_toks);   // 16*2048*768

  // ---- proj: tok = toks @ W_proj + b_proj  (bf16 out), 128x128 MFMA
  k_proj128<<<dim3(8, 256), blk, 0, stream>>>(bt_toks, Wtp, bp, tok);

  // ---- post-proj: U region now reusable. Gate weights + biases.
  k_transpose_to_bf16<<<dim3(64, 32), blk, 0, stream>>>(Wu, Wtur, 2048, 1024);
  k_transpose_to_bf16<<<dim3(64, 32), blk, 0, stream>>>(Wr, Wtur + 1024 * 2048, 2048, 1024);
  k_transpose_to_bf16<<<dim3(64, 32), blk, 0, stream>>>(Wn, Wtn, 2048, 1024);
  hipMemcpyAsync(b_ur, bu, 4096, hipMemcpyDeviceToDevice, stream);
  hipMemcpyAsync(b_ur + 1024, br, 4096, hipMemcpyDeviceToDevice, stream);

  // ---- scores = prev @ tok^T / 32  (batched, mode 4)
  k_gemm_bf16<<<dim3(1, 32, 16), blk, 0, stream>>>(
      psb, 1024, 65536L, tok, 1024, 2097152L, 1024,
      nullptr, 0.03125f, 4, (void*)attn, 2048, 131072L, nullptr, nullptr, nullptr, nullptr);

  k_softmax<<<dim3(1024), blk, 0, stream>>>(attn);

  // ---- routed partials
  k_routed<<<dim3(4, 4, 16), blk, 0, stream>>>(attn, tok, parts);

  // ---- LayerNorms into concat (bf16)
  k_ln_bf16<<<dim3(1024), blk, 0, stream>>>(
      prev, 1, g_st, be_st, conc, 2048, 0, nullptr, 0, 0);
  k_ln_bf16<<<dim3(1024), blk, 0, stream>>>(
      parts, 4, g_in, be_in, conc, 2048, 1024, candA, 2048, 1024);

  // ---- merged u|r gates (mode 5): N=2048 over [Wu^T; Wr^T]
  k_gemm_bf16<<<dim3(16, 32, 1), blk, 0, stream>>>(
      conc, 2048, 0L, Wtur, 2048, 0L, 2048,
      b_ur, 1.0f, 5, (void*)ubuf, 1024, 0L, candA, conc, nullptr, nullptr);

  // ---- new_state = (1-u)*prev + u*tanh(candA @ W_n + b_n)  (mode 3)
  k_gemm_bf16<<<dim3(16, 16, 1), blk, 0, stream>>>(
      candA, 2048, 0L, Wtn, 2048, 0L, 2048,
      bn, 1.0f, 3, (void*)ns, 1024, 0L, nullptr, nullptr, ubuf, prev);

  // ---- final LN -> output (f32)
  k_ln_out<<<dim3(1024), blk, 0, stream>>>(ns, g_o, be_o, out);
}

// Round 3
// 410.606 us; speedup vs baseline: 1.4903x; 1.1925x over previous
//
#include <hip/hip_runtime.h>
#include <stdint.h>

typedef __attribute__((ext_vector_type(4))) float floatx4;
typedef __attribute__((ext_vector_type(8))) short shortx8;

#define LN_EPS 1e-5f

__device__ __forceinline__ unsigned short f2b(float f) {
  unsigned u = __builtin_bit_cast(unsigned, f);
  u = (u + 0x7FFFu + ((u >> 16) & 1u)) >> 16;
  return (unsigned short)u;
}
__device__ __forceinline__ float b2f(unsigned short h) {
  return __builtin_bit_cast(float, (unsigned)h << 16);
}

// async global->LDS 16B: lds dest is wave-uniform base; lane i lands at base + i*16
__device__ __forceinline__ void g2l16(const unsigned short* g, unsigned short* l) {
  __builtin_amdgcn_global_load_lds(
      (const __attribute__((address_space(1))) unsigned int*)g,
      (__attribute__((address_space(3))) unsigned int*)l, 16, 0, 0);
}

// ---------------- block reduction helpers (256 threads = 4 waves) -----------
__device__ __forceinline__ float wave_sum(float v) {
#pragma unroll
  for (int o = 32; o; o >>= 1) v += __shfl_down(v, o, 64);
  return v;
}
__device__ __forceinline__ float wave_max(float v) {
#pragma unroll
  for (int o = 32; o; o >>= 1) v = fmaxf(v, __shfl_down(v, o, 64));
  return v;
}
__device__ __forceinline__ float block_sum(float v, float* s) {
  v = wave_sum(v);
  __syncthreads();
  if ((threadIdx.x & 63) == 0) s[threadIdx.x >> 6] = v;
  __syncthreads();
  return s[0] + s[1] + s[2] + s[3];
}
__device__ __forceinline__ float block_max(float v, float* s) {
  v = wave_max(v);
  __syncthreads();
  if ((threadIdx.x & 63) == 0) s[threadIdx.x >> 6] = v;
  __syncthreads();
  return fmaxf(fmaxf(s[0], s[1]), fmaxf(s[2], s[3]));
}

// ---------------- transpose W (K,N) f32 -> Wt (N,K) bf16 --------------------
__global__ __launch_bounds__(256) void k_transpose_to_bf16(
    const float* __restrict__ in, unsigned short* __restrict__ out, int K, int N) {
  __shared__ float tile[32][33];
  const int k0 = blockIdx.x * 32, n0 = blockIdx.y * 32;
  const int tx = threadIdx.x & 31, ty = threadIdx.x >> 5;  // 32x8
#pragma unroll
  for (int i = 0; i < 32; i += 8)
    tile[ty + i][tx] = in[(long)(k0 + ty + i) * N + n0 + tx];
  __syncthreads();
#pragma unroll
  for (int i = 0; i < 32; i += 8)
    out[(long)(n0 + ty + i) * K + k0 + tx] = f2b(tile[tx][ty + i]);
}

// ---------------- f32 -> bf16 convert ---------------------------------------
__global__ __launch_bounds__(256) void k_cvt_bf16(
    const float* __restrict__ in, unsigned short* __restrict__ out) {
  long i = ((long)blockIdx.x * 256 + threadIdx.x) * 4;
  floatx4 v = *(const floatx4*)(in + i);
  unsigned short t4[4];
#pragma unroll
  for (int j = 0; j < 4; j++) t4[j] = f2b(v[j]);
  *(uint2*)(out + i) = *(uint2*)t4;
}

// ---------------- proj: 128x128 MFMA GEMM, XCD-swizzled grid ----------------
// C[m][n] = A[m][k] * Bt[n][k] + bias[n], bf16 in / bf16 out. K=768, N=1024.
// 1-D grid of 2048 blocks; blocks c, c+8, c+16... land on XCD c (round-robin
// heuristic) -> give each XCD one m-tile across all 8 n-tiles for L2 A-reuse.
__global__ __launch_bounds__(256) void k_proj128(
    const unsigned short* __restrict__ A, const unsigned short* __restrict__ Bt,
    const float* __restrict__ bias, unsigned short* __restrict__ C) {
  constexpr int K = 768;
  constexpr int N = 1024;
  __shared__ unsigned short As[128 * 32];
  __shared__ unsigned short Bs[128 * 32];
  const int tid = threadIdx.x;
  const int wave = tid >> 6, lane = tid & 63;
  const int id = blockIdx.x;
  const int m0 = (((id >> 6) << 3) + (id & 7)) * 128;  // m-tile = grp*8 + xcd
  const int n0 = ((id >> 3) & 7) * 128;                // n-tile = j within xcd
  const int wm = wave & 1, wn = wave >> 1;
  const int l16 = lane & 15, quad = lane >> 4;
  const int srow = lane >> 2;
  const int skc = (lane & 3) * 8;

  floatx4 acc[4][4] = {};

  for (int k0 = 0; k0 < K; k0 += 32) {
#pragma unroll
    for (int j = 0; j < 2; j++) {
      const int reg = wave * 2 + j;
      const int row = reg * 16 + srow;
      g2l16(A + (long)(m0 + row) * K + k0 + skc, &As[reg * 512]);
      g2l16(Bt + (long)(n0 + row) * K + k0 + skc, &Bs[reg * 512]);
    }
    __syncthreads();

    shortx8 af[4], bf[4];
#pragma unroll
    for (int i = 0; i < 4; i++)
      af[i] = *(const shortx8*)&As[(wm * 64 + i * 16 + l16) * 32 + quad * 8];
#pragma unroll
    for (int i = 0; i < 4; i++)
      bf[i] = *(const shortx8*)&Bs[(wn * 64 + i * 16 + l16) * 32 + quad * 8];
#pragma unroll
    for (int i = 0; i < 4; i++)
#pragma unroll
      for (int j = 0; j < 4; j++)
        acc[i][j] = __builtin_amdgcn_mfma_f32_16x16x32_bf16(af[i], bf[j], acc[i][j], 0, 0, 0);
    __syncthreads();
  }

#pragma unroll
  for (int i = 0; i < 4; i++)
#pragma unroll
    for (int j = 0; j < 4; j++) {
      const int rbase = m0 + wm * 64 + i * 16 + quad * 4;
      const int col = n0 + wn * 64 + j * 16 + l16;
      const float bval = bias[col];
#pragma unroll
      for (int r = 0; r < 4; r++)
        C[(long)(rbase + r) * N + col] = f2b(acc[i][j][r] + bval);
    }
}

// ---------------- generic bf16 MFMA GEMM, 64x64 tile, fused epilogues -------
// modes: 3: out f32  = (1-u)*prev + u*tanh(v+bias)      (cand -> new_state)
//        4: out f32  = v*scale         (scores)
//        5: c<1024: out f32 = sigmoid(v+bias) (u); c>=1024: out2 bf16 = sigmoid*psn (r)
__global__ __launch_bounds__(256) void k_gemm_bf16(
    const unsigned short* __restrict__ Aptr, int lda, long sA,
    const unsigned short* __restrict__ Bt, int ldb, long sB, int K,
    const float* __restrict__ bias, float scale, int mode,
    void* __restrict__ out, int ldc, long sC, unsigned short* __restrict__ out2,
    const unsigned short* __restrict__ aux_psn,
    const float* __restrict__ aux_u, const float* __restrict__ aux_prev) {
  __shared__ unsigned short As[64 * 40];
  __shared__ unsigned short Bs[64 * 40];
  const int tid = threadIdx.x;
  const int b = blockIdx.z;
  const int m0 = blockIdx.x * 64, n0 = blockIdx.y * 64;
  const int w = tid >> 6, lane = tid & 63;
  const int wm = w & 1, wn = w >> 1;
  const int l16 = lane & 15, quad = lane >> 4;
  const int srow = tid >> 2, skc = (tid & 3) * 8;

  floatx4 acc[2][2] = {};

  for (int k0 = 0; k0 < K; k0 += 32) {
    {
      const unsigned short* src = Aptr + (long)b * sA + (long)(m0 + srow) * lda + k0 + skc;
      *(uint4*)&As[srow * 40 + skc] = *(const uint4*)src;
    }
    {
      const unsigned short* src = Bt + (long)b * sB + (long)(n0 + srow) * ldb + k0 + skc;
      *(uint4*)&Bs[srow * 40 + skc] = *(const uint4*)src;
    }
    __syncthreads();

    shortx8 a0 = *(const shortx8*)&As[(wm * 32 + 0  + l16) * 40 + quad * 8];
    shortx8 a1 = *(const shortx8*)&As[(wm * 32 + 16 + l16) * 40 + quad * 8];
    shortx8 b0 = *(const shortx8*)&Bs[(wn * 32 + 0  + l16) * 40 + quad * 8];
    shortx8 b1 = *(const shortx8*)&Bs[(wn * 32 + 16 + l16) * 40 + quad * 8];
    acc[0][0] = __builtin_amdgcn_mfma_f32_16x16x32_bf16(a0, b0, acc[0][0], 0, 0, 0);
    acc[0][1] = __builtin_amdgcn_mfma_f32_16x16x32_bf16(a0, b1, acc[0][1], 0, 0, 0);
    acc[1][0] = __builtin_amdgcn_mfma_f32_16x16x32_bf16(a1, b0, acc[1][0], 0, 0, 0);
    acc[1][1] = __builtin_amdgcn_mfma_f32_16x16x32_bf16(a1, b1, acc[1][1], 0, 0, 0);
    __syncthreads();
  }

#pragma unroll
  for (int im = 0; im < 2; im++)
#pragma unroll
    for (int in_ = 0; in_ < 2; in_++) {
      const int rbase = m0 + wm * 32 + im * 16 + quad * 4;
      const int c = n0 + wn * 32 + in_ * 16 + l16;
      const float bval = bias ? bias[c] : 0.0f;
#pragma unroll
      for (int r = 0; r < 4; r++) {
        const int row = rbase + r;
        float v = acc[im][in_][r] * scale + bval;
        const long cidx = (long)b * sC + (long)row * ldc + c;
        if (mode == 3) {
          float cand = tanhf(v);
          float u = aux_u[(long)row * 1024 + c];
          float p = aux_prev[(long)row * 1024 + c];
          ((float*)out)[cidx] = (1.0f - u) * p + u * cand;
        } else if (mode == 4) {
          ((float*)out)[cidx] = v;
        } else {  // mode 5: merged u|r
          if (c < 1024) {
            ((float*)out)[(long)row * 1024 + c] = 1.0f / (1.0f + expf(-v));
          } else {
            const int cc = c - 1024;
            float rr = 1.0f / (1.0f + expf(-v));
            out2[(long)row * 2048 + cc] = f2b(rr * b2f(aux_psn[(long)row * 2048 + cc]));
          }
        }
      }
    }
}

// ---------------- routed = attn_bf16 @ tok via MFMA, K-split x2 -------------
// grid (kc=2, nt=16, b=16). B staged k-major from tok with 66-short row
// stride (2-way max bank aliasing on both u32 staging writes and u16 frag
// reads). parts[kc][b][n][d] f32.
__global__ __launch_bounds__(256) void k_routed_mfma(
    const unsigned short* __restrict__ attnb,  // [16][64][2048] bf16
    const unsigned short* __restrict__ tok,    // [16][2048][1024] bf16
    float* __restrict__ parts) {
  __shared__ unsigned short As[64 * 40];
  __shared__ unsigned short Bs[32 * 66];
  const int kc = blockIdx.x, nt = blockIdx.y, b = blockIdx.z;
  const int tid = threadIdx.x;
  const int wave = tid >> 6, lane = tid & 63;
  const int wm = wave & 1, wn = wave >> 1;
  const int l16 = lane & 15, quad = lane >> 4;
  const int n0 = nt * 64;
  const long abase = (long)b * 131072 + (long)kc * 1024;
  const long tbase = ((long)b * 2048 + (long)kc * 1024) * 1024;
  const int srow = tid >> 2, skc = (tid & 3) * 8;  // A staging: 64 rows x 32 k
  const int bk = tid >> 3, bd = (tid & 7) * 8;     // B staging: 32 k x 64 d

  floatx4 acc[2][2] = {};

  for (int k0 = 0; k0 < 1024; k0 += 32) {
    *(uint4*)&As[srow * 40 + skc] =
        *(const uint4*)(attnb + abase + (long)srow * 2048 + k0 + skc);
    {
      uint4 v = *(const uint4*)(tok + tbase + (long)(k0 + bk) * 1024 + n0 + bd);
      const unsigned* pv = (const unsigned*)&v;
      unsigned short* dst = &Bs[bk * 66 + bd];
#pragma unroll
      for (int w2 = 0; w2 < 4; w2++) *(unsigned*)(dst + w2 * 2) = pv[w2];
    }
    __syncthreads();

    shortx8 a0 = *(const shortx8*)&As[(wm * 32 + 0  + l16) * 40 + quad * 8];
    shortx8 a1 = *(const shortx8*)&As[(wm * 32 + 16 + l16) * 40 + quad * 8];
    shortx8 b0, b1;
#pragma unroll
    for (int j = 0; j < 8; j++) {
      b0[j] = *(const short*)&Bs[(quad * 8 + j) * 66 + wn * 32 + l16];
      b1[j] = *(const short*)&Bs[(quad * 8 + j) * 66 + wn * 32 + 16 + l16];
    }
    acc[0][0] = __builtin_amdgcn_mfma_f32_16x16x32_bf16(a0, b0, acc[0][0], 0, 0, 0);
    acc[0][1] = __builtin_amdgcn_mfma_f32_16x16x32_bf16(a0, b1, acc[0][1], 0, 0, 0);
    acc[1][0] = __builtin_amdgcn_mfma_f32_16x16x32_bf16(a1, b0, acc[1][0], 0, 0, 0);
    acc[1][1] = __builtin_amdgcn_mfma_f32_16x16x32_bf16(a1, b1, acc[1][1], 0, 0, 0);
    __syncthreads();
  }

#pragma unroll
  for (int im = 0; im < 2; im++)
#pragma unroll
    for (int in_ = 0; in_ < 2; in_++) {
      const int rbase = wm * 32 + im * 16 + quad * 4;
      const int c = n0 + wn * 32 + in_ * 16 + l16;
#pragma unroll
      for (int r = 0; r < 4; r++)
        parts[(long)kc * 1048576 + ((long)b * 64 + rbase + r) * 1024 + c] =
            acc[im][in_][r];
    }
}

// ---------------- softmax over S=2048; writes f32-in-place + bf16 copy ------
__global__ __launch_bounds__(256) void k_softmax(
    const float* __restrict__ scores, unsigned short* __restrict__ attnb) {
  __shared__ float scr[4];
  const float* row = scores + (long)blockIdx.x * 2048;
  const int t = threadIdx.x;
  floatx4 a = *(const floatx4*)(row + t * 8);
  floatx4 b = *(const floatx4*)(row + t * 8 + 4);
  float m = -1e30f;
#pragma unroll
  for (int i = 0; i < 4; i++) m = fmaxf(m, fmaxf(a[i], b[i]));
  m = block_max(m, scr);
  float s = 0.f;
#pragma unroll
  for (int i = 0; i < 4; i++) { a[i] = expf(a[i] - m); s += a[i]; b[i] = expf(b[i] - m); s += b[i]; }
  s = block_sum(s, scr);
  const float inv = 1.0f / s;
  unsigned short t8[8];
#pragma unroll
  for (int i = 0; i < 4; i++) { t8[i] = f2b(a[i] * inv); t8[4 + i] = f2b(b[i] * inv); }
  *(uint4*)(attnb + (long)blockIdx.x * 2048 + t * 8) = *(uint4*)t8;
}

// ---------------- LayerNorm (D=1024) -> bf16 target(s) ----------------------
__global__ __launch_bounds__(256) void k_ln_bf16(
    const float* __restrict__ in, int nparts,
    const float* __restrict__ g, const float* __restrict__ be,
    unsigned short* __restrict__ out0, int ld0, int off0,
    unsigned short* __restrict__ out1, int ld1, int off1) {
  __shared__ float scr[4];
  const long r = blockIdx.x;
  const int t = threadIdx.x;
  floatx4 v = {};
  for (int p = 0; p < nparts; p++)
    v += *(const floatx4*)(in + (long)p * 1048576 + r * 1024 + t * 4);
  float s1 = v[0] + v[1] + v[2] + v[3];
  float s2 = v[0] * v[0] + v[1] * v[1] + v[2] * v[2] + v[3] * v[3];
  s1 = block_sum(s1, scr);
  s2 = block_sum(s2, scr);
  const float mean = s1 * (1.0f / 1024.0f);
  const float var = s2 * (1.0f / 1024.0f) - mean * mean;
  const float rstd = rsqrtf(var + LN_EPS);
#pragma unroll
  for (int i = 0; i < 4; i++) {
    const int d = t * 4 + i;
    const float y = (v[i] - mean) * rstd * g[d] + be[d];
    const unsigned short h = f2b(y);
    out0[r * ld0 + off0 + d] = h;
    if (out1) out1[r * ld1 + off1 + d] = h;
  }
}

// ---------------- final LayerNorm -> f32 output ------------------------------
__global__ __launch_bounds__(256) void k_ln_out(
    const float* __restrict__ in, const float* __restrict__ g,
    const float* __restrict__ be, float* __restrict__ out) {
  __shared__ float scr[4];
  const long r = blockIdx.x;
  const int t = threadIdx.x;
  floatx4 v = *(const floatx4*)(in + r * 1024 + t * 4);
  float s1 = v[0] + v[1] + v[2] + v[3];
  float s2 = v[0] * v[0] + v[1] * v[1] + v[2] * v[2] + v[3] * v[3];
  s1 = block_sum(s1, scr);
  s2 = block_sum(s2, scr);
  const float mean = s1 * (1.0f / 1024.0f);
  const float var = s2 * (1.0f / 1024.0f) - mean * mean;
  const float rstd = rsqrtf(var + LN_EPS);
  floatx4 o;
#pragma unroll
  for (int i = 0; i < 4; i++) {
    const int d = t * 4 + i;
    o[i] = (v[i] - mean) * rstd * g[d] + be[d];
  }
  *(floatx4*)(out + r * 1024 + t * 4) = o;
}

// ---------------------------------------------------------------------------
extern "C" void kernel_launch(void* const* d_in, const int* in_sizes, int n_in,
                              void* d_out, int out_size, void* d_ws, size_t ws_size,
                              hipStream_t stream) {
  (void)in_sizes; (void)n_in; (void)out_size; (void)ws_size;
  const float* prev  = (const float*)d_in[0];
  const float* toks  = (const float*)d_in[1];
  const float* Wp    = (const float*)d_in[2];
  const float* bp    = (const float*)d_in[3];
  const float* g_st  = (const float*)d_in[4];
  const float* be_st = (const float*)d_in[5];
  const float* g_in  = (const float*)d_in[6];
  const float* be_in = (const float*)d_in[7];
  const float* g_o   = (const float*)d_in[8];
  const float* be_o  = (const float*)d_in[9];
  const float* Wu    = (const float*)d_in[10];
  const float* bu    = (const float*)d_in[11];
  const float* Wr    = (const float*)d_in[12];
  const float* br    = (const float*)d_in[13];
  const float* Wn    = (const float*)d_in[14];
  const float* bn    = (const float*)d_in[15];
  float* out = (float*)d_out;

  // ---- workspace (~118 MB). Region U aliases bt_toks (dead after proj).
  char* ws = (char*)d_ws;
  unsigned short* tok   = (unsigned short*)ws; ws += 67108864;   // 32768x1024 bf16
  unsigned short* Wtp   = (unsigned short*)ws; ws += 1572864;    // 1024x768 bf16
  unsigned short* psb   = (unsigned short*)ws; ws += 2097152;    // 1024x1024 bf16
  char* U = ws;
  unsigned short* bt_toks = (unsigned short*)U;                  // 32768x768 bf16 (50.3MB)
  char* u = U;
  float*          attn  = (float*)u;          u += 8388608;      // 16x64x2048 f32
  unsigned short* attnb = (unsigned short*)u; u += 4194304;      // 16x64x2048 bf16
  float*          parts = (float*)u;          u += 8388608;      // 2x 1024x1024 f32
  unsigned short* conc  = (unsigned short*)u; u += 4194304;      // 1024x2048 bf16
  unsigned short* candA = (unsigned short*)u; u += 4194304;      // 1024x2048 bf16
  float*          ubuf  = (float*)u;          u += 4194304;      // 1024x1024 f32
  float*          ns    = (float*)u;          u += 4194304;      // 1024x1024 f32
  unsigned short* Wtur  = (unsigned short*)u; u += 8388608;      // 2048x2048 bf16
  unsigned short* Wtn   = (unsigned short*)u; u += 4194304;      // 1024x2048 bf16
  float*          b_ur  = (float*)u;          u += 8192;         // 2048 f32

  const dim3 blk(256);

  // ---- pre-proj conversions
  k_transpose_to_bf16<<<dim3(24, 32), blk, 0, stream>>>(Wp, Wtp, 768, 1024);
  k_cvt_bf16<<<dim3(1024), blk, 0, stream>>>(prev, psb);
  k_cvt_bf16<<<dim3(24576), blk, 0, stream>>>(toks, bt_toks);   // 16*2048*768

  // ---- proj: tok = toks @ W_proj + b_proj  (bf16 out), XCD-swizzled 128x128
  k_proj128<<<dim3(2048), blk, 0, stream>>>(bt_toks, Wtp, bp, tok);

  // ---- post-proj: U region reusable. Gate weights + biases.
  k_transpose_to_bf16<<<dim3(64, 32), blk, 0, stream>>>(Wu, Wtur, 2048, 1024);
  k_transpose_to_bf16<<<dim3(64, 32), blk, 0, stream>>>(Wr, Wtur + 1024 * 2048, 2048, 1024);
  k_transpose_to_bf16<<<dim3(64, 32), blk, 0, stream>>>(Wn, Wtn, 2048, 1024);
  hipMemcpyAsync(b_ur, bu, 4096, hipMemcpyDeviceToDevice, stream);
  hipMemcpyAsync(b_ur + 1024, br, 4096, hipMemcpyDeviceToDevice, stream);

  // ---- scores = prev @ tok^T / 32  (batched, mode 4)
  k_gemm_bf16<<<dim3(1, 32, 16), blk, 0, stream>>>(
      psb, 1024, 65536L, tok, 1024, 2097152L, 1024,
      nullptr, 0.03125f, 4, (void*)attn, 2048, 131072L, nullptr, nullptr, nullptr, nullptr);

  // ---- softmax (f32 in, bf16 out)
  k_softmax<<<dim3(1024), blk, 0, stream>>>(attn, attnb);

  // ---- routed partials via MFMA (K-split x2)
  k_routed_mfma<<<dim3(2, 16, 16), blk, 0, stream>>>(attnb, tok, parts);

  // ---- LayerNorms into concat (bf16)
  k_ln_bf16<<<dim3(1024), blk, 0, stream>>>(
      prev, 1, g_st, be_st, conc, 2048, 0, nullptr, 0, 0);
  k_ln_bf16<<<dim3(1024), blk, 0, stream>>>(
      parts, 2, g_in, be_in, conc, 2048, 1024, candA, 2048, 1024);

  // ---- merged u|r gates (mode 5): N=2048 over [Wu^T; Wr^T]
  k_gemm_bf16<<<dim3(16, 32, 1), blk, 0, stream>>>(
      conc, 2048, 0L, Wtur, 2048, 0L, 2048,
      b_ur, 1.0f, 5, (void*)ubuf, 1024, 0L, candA, conc, nullptr, nullptr);

  // ---- new_state = (1-u)*prev + u*tanh(candA @ W_n + b_n)  (mode 3)
  k_gemm_bf16<<<dim3(16, 16, 1), blk, 0, stream>>>(
      candA, 2048, 0L, Wtn, 2048, 0L, 2048,
      bn, 1.0f, 3, (void*)ns, 1024, 0L, nullptr, nullptr, ubuf, prev);

  // ---- final LN -> output (f32)
  k_ln_out<<<dim3(1024), blk, 0, stream>>>(ns, g_o, be_o, out);
}